// Round 2
// baseline (699.169 us; speedup 1.0000x reference)
//
#include <hip/hip_runtime.h>
#include <hip/hip_bf16.h>

#define SQL  2048
#define SKVL 4096
#define DIML 1024

typedef __attribute__((ext_vector_type(8))) short short8;
typedef __attribute__((ext_vector_type(4))) float f32x4;

__device__ __forceinline__ short f2s(float f) {
  return __builtin_bit_cast(short, __float2bfloat16(f));
}
__device__ __forceinline__ float s2f(short s) {
  return __bfloat162float(__builtin_bit_cast(__hip_bfloat16, s));
}

// swizzled LDS address for 128-byte-stride rows (kills bank conflicts on b128 reads)
__device__ __forceinline__ char* swz_addr(char* base, int row, int colByte) {
  return base + (row * 128 + (colByte ^ ((row & 7) << 4)));
}

// ---------------- x (f32) -> bf16 ----------------
__global__ __launch_bounds__(256) void convert_x_kernel(
    const float* __restrict__ x, short* __restrict__ xbf)
{
  const size_t i = ((size_t)blockIdx.x * 256 + threadIdx.x) * 8;
  float4 a = *(const float4*)&x[i];
  float4 b = *(const float4*)&x[i + 4];
  short8 o;
  o[0] = f2s(a.x); o[1] = f2s(a.y); o[2] = f2s(a.z); o[3] = f2s(a.w);
  o[4] = f2s(b.x); o[5] = f2s(b.y); o[6] = f2s(b.z); o[7] = f2s(b.w);
  *(short8*)&xbf[i] = o;
}

// ---------------- weight transpose+convert: WT[n][k] = bf16(W[k][n]) ----------------
__global__ __launch_bounds__(256) void transpose_w_kernel(
    const float* __restrict__ W0, const float* __restrict__ W1,
    const float* __restrict__ W2, const float* __restrict__ W3,
    short* __restrict__ WT)
{
  __shared__ float T[64][68];
  const int bid = blockIdx.x;
  const int w = bid >> 8;
  const float* W = (w == 0) ? W0 : (w == 1) ? W1 : (w == 2) ? W2 : W3;
  short* D = WT + (size_t)w * 1048576;
  const int tile = bid & 255;
  const int r0 = (tile >> 4) * 64;  // k block
  const int c0 = (tile & 15) * 64;  // n block
  const int t = threadIdx.x;
  const int row = t >> 2;
  const int q = t & 3;
#pragma unroll
  for (int i = 0; i < 4; i++)
    *(float4*)&T[row][q * 16 + i * 4] =
        *(const float4*)&W[(size_t)(r0 + row) * 1024 + c0 + q * 16 + i * 4];
  __syncthreads();
  short8 o0, o1;
#pragma unroll
  for (int j = 0; j < 8; j++) {
    o0[j] = f2s(T[q * 16 + j][row]);
    o1[j] = f2s(T[q * 16 + 8 + j][row]);
  }
  *(short8*)&D[(size_t)(c0 + row) * 1024 + r0 + q * 16] = o0;
  *(short8*)&D[(size_t)(c0 + row) * 1024 + r0 + q * 16 + 8] = o1;
}

// ---------------- copy k_cache/v_cache (f32) into d_out k/v regions ----------------
__global__ __launch_bounds__(256) void copy_cache_kernel(
    const float* __restrict__ kc, const float* __restrict__ vc,
    float* __restrict__ out)
{
  const int idx = blockIdx.x * 256 + threadIdx.x;  // 0 .. 1048575
  const int tensor = idx >> 19;
  const int cc = idx & 524287;
  const size_t e = (size_t)cc * 8;          // element in cache [B][2048][1024]
  const int b = (int)(e >> 21);
  const size_t rem = e & 2097151;
  const float* src = tensor ? vc : kc;
  float* dst = out + (tensor ? 12582912u : 4194304u) + (size_t)b * 4194304u + rem;
  *(float4*)dst       = *(const float4*)&src[e];
  *(float4*)(dst + 4) = *(const float4*)&src[e + 4];
}

// ---------------- GEMM: C = A(bf16)[4096,1024] * BT^T + bias(f32) ----------------
// BT is bf16 [N][K]. drow = (row>>11)*dst_batch_rows + dst_row0 + (row&2047).
// Cf (f32) or Cb (bf16): exactly one non-null.
__global__ __launch_bounds__(256) void gemm_bt_bias(
    const short* __restrict__ A,
    const short* __restrict__ BT,
    const float* __restrict__ bias,
    float* __restrict__ Cf,
    short* __restrict__ Cb,
    int dst_batch_rows, int dst_row0)
{
  constexpr int K = 1024;
  __shared__ __align__(16) short As[128 * 32];
  __shared__ __align__(16) short Bs[128 * 32];
  const int tid = threadIdx.x;
  const int lane = tid & 63;
  const int wave = tid >> 6;
  const int bid = blockIdx.x;
  const int nb = bid & 7;
  const int mb = bid >> 3;
  const int wm = wave >> 1;
  const int wn = wave & 1;
  const int g = lane >> 4;
  const int fr = lane & 15;

  f32x4 acc[4][4] = {};

  const int c0 = tid, c1 = tid + 256;
  const short* Ab0 = A + (size_t)(mb * 128 + (c0 >> 2)) * K + (c0 & 3) * 8;
  const short* Ab1 = A + (size_t)(mb * 128 + (c1 >> 2)) * K + (c1 & 3) * 8;
  const short* Bb0 = BT + (size_t)(nb * 128 + (c0 >> 2)) * K + (c0 & 3) * 8;
  const short* Bb1 = BT + (size_t)(nb * 128 + (c1 >> 2)) * K + (c1 & 3) * 8;

  for (int k0 = 0; k0 < K; k0 += 32) {
    __syncthreads();
    *(short8*)&As[c0 * 8] = *(const short8*)&Ab0[k0];
    *(short8*)&As[c1 * 8] = *(const short8*)&Ab1[k0];
    *(short8*)&Bs[c0 * 8] = *(const short8*)&Bb0[k0];
    *(short8*)&Bs[c1 * 8] = *(const short8*)&Bb1[k0];
    __syncthreads();
    short8 af[4], bfv[4];
#pragma unroll
    for (int m = 0; m < 4; m++)
      af[m] = *(const short8*)&As[(wm * 64 + m * 16 + fr) * 32 + g * 8];
#pragma unroll
    for (int n = 0; n < 4; n++)
      bfv[n] = *(const short8*)&Bs[(wn * 64 + n * 16 + fr) * 32 + g * 8];
#pragma unroll
    for (int m = 0; m < 4; m++)
#pragma unroll
      for (int n = 0; n < 4; n++)
        acc[m][n] = __builtin_amdgcn_mfma_f32_16x16x32_bf16(af[m], bfv[n], acc[m][n], 0, 0, 0);
  }

  const int gm = mb * 128 + wm * 64;
  const int gn = nb * 128 + wn * 64;
  float bv[4];
#pragma unroll
  for (int n = 0; n < 4; n++) bv[n] = bias[gn + n * 16 + fr];
#pragma unroll
  for (int m = 0; m < 4; m++) {
#pragma unroll
    for (int r = 0; r < 4; r++) {
      const int row = gm + m * 16 + g * 4 + r;
      const int drow = (row >> 11) * dst_batch_rows + dst_row0 + (row & 2047);
      if (Cb) {
#pragma unroll
        for (int n = 0; n < 4; n++)
          Cb[(size_t)drow * 1024 + gn + n * 16 + fr] = f2s(acc[m][n][r] + bv[n]);
      } else {
#pragma unroll
        for (int n = 0; n < 4; n++)
          Cf[(size_t)drow * 1024 + gn + n * 16 + fr] = acc[m][n][r] + bv[n];
      }
    }
  }
}

// ---------------- flash attention: 4 waves x 16 q-rows, KVBLK=64 ----------------
// Q bf16; K,V f32 (d_out k/v regions, fully written); mask f32; out Ctx bf16.
__global__ __launch_bounds__(256) void attn_kernel(
    const short* __restrict__ Q,
    const float* __restrict__ Kf,
    const float* __restrict__ Vf,
    const float* __restrict__ mask,
    short* __restrict__ O)
{
  __shared__ __align__(16) char VT[64 * 128];      // V^T tile [hd][kv] bf16, swizzled
  __shared__ __align__(16) char Pl[4 * 16 * 128];  // per-wave P [16][64] bf16, swizzled
  const int tid = threadIdx.x;
  const int lane = tid & 63;
  const int wave = tid >> 6;
  const int bid = blockIdx.x;
  const int qb = bid & 31;
  const int bh = bid >> 5;
  const int b = bh >> 4;
  const int h = bh & 15;
  const int q0 = qb * 64 + wave * 16;
  const int g = lane >> 4;
  const int c = lane & 15;
  char* PlW = Pl + wave * (16 * 128);

  short8 qf[2];
  {
    const short* qp = Q + (size_t)(b * SQL + q0 + c) * DIML + h * 64 + g * 8;
    qf[0] = *(const short8*)qp;
    qf[1] = *(const short8*)(qp + 32);
  }

  float m_run[4] = {-1e30f, -1e30f, -1e30f, -1e30f};
  float l_run[4] = {0.f, 0.f, 0.f, 0.f};
  f32x4 ctxa[4] = {};

  const float* Kb = Kf + (size_t)b * SKVL * DIML + h * 64;
  const float* Vb = Vf + (size_t)b * SKVL * DIML + h * 64;
  const float* Mb = mask + (size_t)(b * SQL + q0 + g * 4) * SKVL;

  const int vrow = tid >> 2;        // kv row 0..63
  const int vq = (tid & 3) * 16;    // d-seg start

  for (int kt = 0; kt < SKVL; kt += 64) {
    // load V tile (f32), convert, stage transposed+swizzled
    const float* vp = Vb + (size_t)(kt + vrow) * DIML + vq;
    float4 va = *(const float4*)vp;
    float4 vb2 = *(const float4*)(vp + 4);
    float4 vc2 = *(const float4*)(vp + 8);
    float4 vd = *(const float4*)(vp + 12);
    float vv[16] = {va.x, va.y, va.z, va.w, vb2.x, vb2.y, vb2.z, vb2.w,
                    vc2.x, vc2.y, vc2.z, vc2.w, vd.x, vd.y, vd.z, vd.w};
    __syncthreads();  // everyone done reading previous VT
#pragma unroll
    for (int j = 0; j < 16; j++)
      *(short*)swz_addr(VT, vq + j, vrow * 2) = f2s(vv[j]);
    __syncthreads();  // VT ready

    // QK^T: K rows straight from global f32 (L2-resident), packed to bf16
    f32x4 s[4] = {};
#pragma unroll
    for (int n = 0; n < 4; n++) {
      const float* kp = Kb + (size_t)(kt + n * 16 + c) * DIML + g * 8;
      float4 a0 = *(const float4*)kp;
      float4 a1 = *(const float4*)(kp + 4);
      float4 b0 = *(const float4*)(kp + 32);
      float4 b1 = *(const float4*)(kp + 36);
      short8 k0, k1;
      k0[0] = f2s(a0.x); k0[1] = f2s(a0.y); k0[2] = f2s(a0.z); k0[3] = f2s(a0.w);
      k0[4] = f2s(a1.x); k0[5] = f2s(a1.y); k0[6] = f2s(a1.z); k0[7] = f2s(a1.w);
      k1[0] = f2s(b0.x); k1[1] = f2s(b0.y); k1[2] = f2s(b0.z); k1[3] = f2s(b0.w);
      k1[4] = f2s(b1.x); k1[5] = f2s(b1.y); k1[6] = f2s(b1.z); k1[7] = f2s(b1.w);
      s[n] = __builtin_amdgcn_mfma_f32_16x16x32_bf16(qf[0], k0, s[n], 0, 0, 0);
      s[n] = __builtin_amdgcn_mfma_f32_16x16x32_bf16(qf[1], k1, s[n], 0, 0, 0);
    }
    // scale + additive mask (f32)
#pragma unroll
    for (int r = 0; r < 4; r++) {
#pragma unroll
      for (int n = 0; n < 4; n++) {
        float mv = Mb[(size_t)r * SKVL + kt + n * 16 + c];
        s[n][r] = s[n][r] * 0.125f + mv * (-10000.0f);
      }
    }
    // online softmax (row stats across the 16-lane column group)
#pragma unroll
    for (int r = 0; r < 4; r++) {
      float mt = fmaxf(fmaxf(s[0][r], s[1][r]), fmaxf(s[2][r], s[3][r]));
#pragma unroll
      for (int off = 1; off < 16; off <<= 1) mt = fmaxf(mt, __shfl_xor(mt, off));
      const float mnew = fmaxf(m_run[r], mt);
      const float sc = __expf(m_run[r] - mnew);
      m_run[r] = mnew;
      float ps = 0.f;
#pragma unroll
      for (int n = 0; n < 4; n++) {
        float p = __expf(s[n][r] - mnew);
        s[n][r] = p;
        ps += p;
      }
#pragma unroll
      for (int off = 1; off < 16; off <<= 1) ps += __shfl_xor(ps, off);
      l_run[r] = l_run[r] * sc + ps;
#pragma unroll
      for (int n = 0; n < 4; n++) ctxa[n][r] *= sc;
    }
    // P -> LDS (bf16, wave-private, swizzled) to re-layout for PV A-operand
#pragma unroll
    for (int r = 0; r < 4; r++)
#pragma unroll
      for (int n = 0; n < 4; n++)
        *(short*)swz_addr(PlW, g * 4 + r, (n * 16 + c) * 2) = f2s(s[n][r]);
    // PV
#pragma unroll
    for (int ks = 0; ks < 2; ks++) {
      short8 pa = *(short8*)swz_addr(PlW, c, ks * 64 + g * 16);
#pragma unroll
      for (int n = 0; n < 4; n++) {
        short8 vbf = *(short8*)swz_addr(VT, n * 16 + c, ks * 64 + g * 16);
        ctxa[n] = __builtin_amdgcn_mfma_f32_16x16x32_bf16(pa, vbf, ctxa[n], 0, 0, 0);
      }
    }
  }

#pragma unroll
  for (int r = 0; r < 4; r++) {
    const float inv = 1.0f / l_run[r];
#pragma unroll
    for (int n = 0; n < 4; n++)
      O[(size_t)(b * SQL + q0 + g * 4 + r) * DIML + h * 64 + n * 16 + c] =
          f2s(ctxa[n][r] * inv);
  }
}

extern "C" void kernel_launch(void* const* d_in, const int* in_sizes, int n_in,
                              void* d_out, int out_size, void* d_ws, size_t ws_size,
                              hipStream_t stream)
{
  const float* x   = (const float*)d_in[0];
  const float* kc  = (const float*)d_in[1];
  const float* vc  = (const float*)d_in[2];
  const float* msk = (const float*)d_in[3];
  const float* Wq  = (const float*)d_in[4];
  const float* bq  = (const float*)d_in[5];
  const float* Wk  = (const float*)d_in[6];
  const float* bk  = (const float*)d_in[7];
  const float* Wv  = (const float*)d_in[8];
  const float* bv  = (const float*)d_in[9];
  const float* Wo  = (const float*)d_in[10];
  const float* bo  = (const float*)d_in[11];

  float* outf = (float*)d_out;
  float* kout = outf + 4194304;    // [B][4096][1024] f32
  float* vout = outf + 12582912;

  short* ws_s = (short*)d_ws;
  short* WT   = ws_s;                          // 4 x [1024][1024] bf16
  short* xbf  = ws_s + (size_t)4 * 1048576;    // [4096][1024] bf16
  short* qbf  = ws_s + (size_t)8 * 1048576;    // [4096][1024] bf16
  short* ctxb = xbf;                           // reuse x_bf after QKV gemms

  convert_x_kernel<<<2048, 256, 0, stream>>>(x, xbf);
  transpose_w_kernel<<<1024, 256, 0, stream>>>(Wq, Wk, Wv, Wo, WT);
  copy_cache_kernel<<<4096, 256, 0, stream>>>(kc, vc, outf);
  gemm_bt_bias<<<256, 256, 0, stream>>>(xbf, WT,               bq, nullptr, qbf, 2048, 0);
  gemm_bt_bias<<<256, 256, 0, stream>>>(xbf, WT + 1048576,     bk, kout, nullptr, 4096, 2048);
  gemm_bt_bias<<<256, 256, 0, stream>>>(xbf, WT + 2 * 1048576, bv, vout, nullptr, 4096, 2048);
  attn_kernel<<<1024, 256, 0, stream>>>(qbf, kout, vout, msk, ctxb);
  gemm_bt_bias<<<256, 256, 0, stream>>>(ctxb, WT + 3 * 1048576, bo, outf, nullptr, 2048, 0);
}

// Round 3
// 641.908 us; speedup vs baseline: 1.0892x; 1.0892x over previous
//
#include <hip/hip_runtime.h>
#include <hip/hip_bf16.h>

#define SQL  2048
#define SKVL 4096
#define DIML 1024

typedef __attribute__((ext_vector_type(8))) short short8;
typedef __attribute__((ext_vector_type(4))) float f32x4;

__device__ __forceinline__ short f2s(float f) {
  return __builtin_bit_cast(short, __float2bfloat16(f));
}

// swizzled LDS address for 128-byte-stride rows
__device__ __forceinline__ char* swz_addr(char* base, int row, int colByte) {
  return base + (row * 128 + (colByte ^ ((row & 7) << 4)));
}

// ---------------- x (f32) -> bf16 ----------------
__global__ __launch_bounds__(256) void convert_x_kernel(
    const float* __restrict__ x, short* __restrict__ xbf)
{
  const size_t i = ((size_t)blockIdx.x * 256 + threadIdx.x) * 8;
  float4 a = *(const float4*)&x[i];
  float4 b = *(const float4*)&x[i + 4];
  short8 o;
  o[0] = f2s(a.x); o[1] = f2s(a.y); o[2] = f2s(a.z); o[3] = f2s(a.w);
  o[4] = f2s(b.x); o[5] = f2s(b.y); o[6] = f2s(b.z); o[7] = f2s(b.w);
  *(short8*)&xbf[i] = o;
}

// ---------------- weight transpose+convert: WT[n][k] = bf16(W[k][n]) ----------------
__global__ __launch_bounds__(256) void transpose_w_kernel(
    const float* __restrict__ W0, const float* __restrict__ W1,
    const float* __restrict__ W2, const float* __restrict__ W3,
    short* __restrict__ WT)
{
  __shared__ float T[64][65];
  const int bid = blockIdx.x;
  const int w = bid >> 8;
  const float* W = (w == 0) ? W0 : (w == 1) ? W1 : (w == 2) ? W2 : W3;
  short* D = WT + (size_t)w * 1048576;
  const int tile = bid & 255;
  const int r0 = (tile >> 4) * 64;
  const int c0 = (tile & 15) * 64;
  const int t = threadIdx.x;
  const int row = t >> 2;
  const int q = t & 3;
#pragma unroll
  for (int i = 0; i < 4; i++)
    *(float4*)&T[row][q * 16 + i * 4] =
        *(const float4*)&W[(size_t)(r0 + row) * 1024 + c0 + q * 16 + i * 4];
  __syncthreads();
  short8 o0, o1;
#pragma unroll
  for (int j = 0; j < 8; j++) {
    o0[j] = f2s(T[q * 16 + j][row]);
    o1[j] = f2s(T[q * 16 + 8 + j][row]);
  }
  *(short8*)&D[(size_t)(c0 + row) * 1024 + r0 + q * 16] = o0;
  *(short8*)&D[(size_t)(c0 + row) * 1024 + r0 + q * 16 + 8] = o1;
}

// ---------------- copy caches into d_out (f32) + K cache rows into Kbf (bf16) ----------------
__global__ __launch_bounds__(256) void copy_cache_kernel(
    const float* __restrict__ kc, const float* __restrict__ vc,
    float* __restrict__ out, short* __restrict__ Kbf)
{
  const int idx = blockIdx.x * 256 + threadIdx.x;  // 0 .. 1048575
  const int tensor = idx >> 19;
  const int cc = idx & 524287;
  const size_t e = (size_t)cc * 8;          // element in cache [B][2048][1024]
  const int b = (int)(e >> 21);
  const size_t rem = e & 2097151;
  const float* src = tensor ? vc : kc;
  float* dst = out + (tensor ? 12582912u : 4194304u) + (size_t)b * 4194304u + rem;
  float4 a = *(const float4*)&src[e];
  float4 bb = *(const float4*)&src[e + 4];
  *(float4*)dst = a;
  *(float4*)(dst + 4) = bb;
  if (tensor == 0) {
    short8 o;
    o[0] = f2s(a.x); o[1] = f2s(a.y); o[2] = f2s(a.z); o[3] = f2s(a.w);
    o[4] = f2s(bb.x); o[5] = f2s(bb.y); o[6] = f2s(bb.z); o[7] = f2s(bb.w);
    *(short8*)&Kbf[(size_t)b * 4194304u + rem] = o;
  }
}

// ---------------- GEMM: C = A(bf16)[4096,1024] * BT^T + bias(f32) ----------------
// drow = (row>>11)*dst_batch_rows + dst_row0 + (row&2047). Cf f32 and/or Cb bf16.
__global__ __launch_bounds__(256) void gemm_bt_bias(
    const short* __restrict__ A,
    const short* __restrict__ BT,
    const float* __restrict__ bias,
    float* __restrict__ Cf,
    short* __restrict__ Cb,
    int dst_batch_rows, int dst_row0, float oscale)
{
  constexpr int K = 1024;
  __shared__ __align__(16) short As[128 * 32];
  __shared__ __align__(16) short Bs[128 * 32];
  const int tid = threadIdx.x;
  const int lane = tid & 63;
  const int wave = tid >> 6;
  const int bid = blockIdx.x;
  const int nb = bid & 7;
  const int mb = bid >> 3;
  const int wm = wave >> 1;
  const int wn = wave & 1;
  const int g = lane >> 4;
  const int fr = lane & 15;

  f32x4 acc[4][4] = {};

  const int c0 = tid, c1 = tid + 256;
  const short* Ab0 = A + (size_t)(mb * 128 + (c0 >> 2)) * K + (c0 & 3) * 8;
  const short* Ab1 = A + (size_t)(mb * 128 + (c1 >> 2)) * K + (c1 & 3) * 8;
  const short* Bb0 = BT + (size_t)(nb * 128 + (c0 >> 2)) * K + (c0 & 3) * 8;
  const short* Bb1 = BT + (size_t)(nb * 128 + (c1 >> 2)) * K + (c1 & 3) * 8;

  for (int k0 = 0; k0 < K; k0 += 32) {
    __syncthreads();
    *(short8*)&As[c0 * 8] = *(const short8*)&Ab0[k0];
    *(short8*)&As[c1 * 8] = *(const short8*)&Ab1[k0];
    *(short8*)&Bs[c0 * 8] = *(const short8*)&Bb0[k0];
    *(short8*)&Bs[c1 * 8] = *(const short8*)&Bb1[k0];
    __syncthreads();
    short8 af[4], bfv[4];
#pragma unroll
    for (int m = 0; m < 4; m++)
      af[m] = *(const short8*)&As[(wm * 64 + m * 16 + fr) * 32 + g * 8];
#pragma unroll
    for (int n = 0; n < 4; n++)
      bfv[n] = *(const short8*)&Bs[(wn * 64 + n * 16 + fr) * 32 + g * 8];
#pragma unroll
    for (int m = 0; m < 4; m++)
#pragma unroll
      for (int n = 0; n < 4; n++)
        acc[m][n] = __builtin_amdgcn_mfma_f32_16x16x32_bf16(af[m], bfv[n], acc[m][n], 0, 0, 0);
  }

  const int gm = mb * 128 + wm * 64;
  const int gn = nb * 128 + wn * 64;
  float bv[4];
#pragma unroll
  for (int n = 0; n < 4; n++) bv[n] = bias[gn + n * 16 + fr];
#pragma unroll
  for (int m = 0; m < 4; m++) {
#pragma unroll
    for (int r = 0; r < 4; r++) {
      const int row = gm + m * 16 + g * 4 + r;
      const int drow = (row >> 11) * dst_batch_rows + dst_row0 + (row & 2047);
      float vals[4];
#pragma unroll
      for (int n = 0; n < 4; n++) vals[n] = (acc[m][n][r] + bv[n]) * oscale;
      if (Cf) {
#pragma unroll
        for (int n = 0; n < 4; n++)
          Cf[(size_t)drow * 1024 + gn + n * 16 + fr] = vals[n];
      }
      if (Cb) {
#pragma unroll
        for (int n = 0; n < 4; n++)
          Cb[(size_t)drow * 1024 + gn + n * 16 + fr] = f2s(vals[n]);
      }
    }
  }
}

// ---------------- V (f32, d_out region) -> VT bf16 [B*H][64][SKVL] ----------------
__global__ __launch_bounds__(256) void transpose_v_kernel(
    const float* __restrict__ Vf, short* __restrict__ VT)
{
  __shared__ float T[64][65];
  const int bid = blockIdx.x;      // b(2) x h(16) x kb(64)
  const int kb = bid & 63;
  const int h = (bid >> 6) & 15;
  const int b = bid >> 10;
  const int kt = kb * 64;
  const int t = threadIdx.x;
  const int row = t >> 2;
  const int q = t & 3;
  const float* src = Vf + (size_t)(b * SKVL + kt + row) * DIML + h * 64 + q * 16;
#pragma unroll
  for (int i = 0; i < 4; i++)
    *(float4*)&T[row][q * 16 + i * 4] = *(const float4*)&src[i * 4];
  __syncthreads();
  short8 o0, o1;
#pragma unroll
  for (int j = 0; j < 8; j++) {
    o0[j] = f2s(T[q * 16 + j][row]);
    o1[j] = f2s(T[q * 16 + 8 + j][row]);
  }
  short* D = VT + (size_t)((b * 16 + h) * 64 + row) * SKVL + kt;
  *(short8*)&D[q * 16] = o0;
  *(short8*)&D[q * 16 + 8] = o1;
}

// ---------------- flash attention: 4 waves x 16 q-rows, KVBLK=64, no barriers ----------------
// Q bf16 (pre-scaled by 0.125); K bf16 [B][SKVL][DIML]; VT bf16 [B*H][64][SKVL];
// mask f32; out ctx bf16.
__global__ __launch_bounds__(256) void attn_kernel(
    const short* __restrict__ Q,
    const short* __restrict__ Kb_,
    const short* __restrict__ VT_,
    const float* __restrict__ mask,
    short* __restrict__ O)
{
  __shared__ __align__(16) char Pl[2][4][16 * 128];  // [parity][wave][P 16x64 bf16 swz]
  const int tid = threadIdx.x;
  const int lane = tid & 63;
  const int wave = tid >> 6;
  const int bid = blockIdx.x;
  const int qb = bid & 31;
  const int bh = bid >> 5;
  const int b = bh >> 4;
  const int h = bh & 15;
  const int q0 = qb * 64 + wave * 16;
  const int g = lane >> 4;
  const int c = lane & 15;

  short8 qf[2];
  {
    const short* qp = Q + (size_t)(b * SQL + q0 + c) * DIML + h * 64 + g * 8;
    qf[0] = *(const short8*)qp;
    qf[1] = *(const short8*)(qp + 32);
  }

  float m_run[4] = {-1e30f, -1e30f, -1e30f, -1e30f};
  float lpart[4] = {0.f, 0.f, 0.f, 0.f};  // per-lane partial row sums
  f32x4 ctxa[4] = {};

  const short* Kp = Kb_ + (size_t)b * SKVL * DIML + h * 64;
  const short* Vp = VT_ + (size_t)(b * 16 + h) * 64 * SKVL;
  const float* Mb = mask + (size_t)(b * SQL + q0 + g * 4) * SKVL;

  for (int kt = 0; kt < SKVL; kt += 64) {
    char* PlW = &Pl[(kt >> 6) & 1][wave][0];
    // QK^T from bf16 K (global, L2/L3-resident)
    f32x4 s[4] = {};
#pragma unroll
    for (int n = 0; n < 4; n++) {
      const short* kp = Kp + (size_t)(kt + n * 16 + c) * DIML + g * 8;
      short8 k0 = *(const short8*)kp;
      short8 k1 = *(const short8*)(kp + 32);
      s[n] = __builtin_amdgcn_mfma_f32_16x16x32_bf16(qf[0], k0, s[n], 0, 0, 0);
      s[n] = __builtin_amdgcn_mfma_f32_16x16x32_bf16(qf[1], k1, s[n], 0, 0, 0);
    }
    // additive mask (Q pre-scaled, so no score scale here)
#pragma unroll
    for (int r = 0; r < 4; r++)
#pragma unroll
      for (int n = 0; n < 4; n++)
        s[n][r] = fmaf(Mb[(size_t)r * SKVL + kt + n * 16 + c], -10000.0f, s[n][r]);

    // defer-max: lane-local check, wave-uniform rescale only when max grows
    float mloc[4];
#pragma unroll
    for (int r = 0; r < 4; r++)
      mloc[r] = fmaxf(fmaxf(s[0][r], s[1][r]), fmaxf(s[2][r], s[3][r]));
    const int grow = (mloc[0] > m_run[0] + 8.f) || (mloc[1] > m_run[1] + 8.f) ||
                     (mloc[2] > m_run[2] + 8.f) || (mloc[3] > m_run[3] + 8.f);
    if (__any(grow)) {
#pragma unroll
      for (int r = 0; r < 4; r++) {
        float mt = mloc[r];
#pragma unroll
        for (int off = 1; off < 16; off <<= 1) mt = fmaxf(mt, __shfl_xor(mt, off));
        const float mnew = fmaxf(m_run[r], mt);
        const float sc = __expf(m_run[r] - mnew);
        m_run[r] = mnew;
        lpart[r] *= sc;
        ctxa[0][r] *= sc; ctxa[1][r] *= sc; ctxa[2][r] *= sc; ctxa[3][r] *= sc;
      }
    }
    // exp + per-lane partial sum + pack P (bf16) into wave-private LDS
#pragma unroll
    for (int r = 0; r < 4; r++) {
#pragma unroll
      for (int n = 0; n < 4; n++) {
        float p = __expf(s[n][r] - m_run[r]);
        lpart[r] += p;
        *(short*)swz_addr(PlW, g * 4 + r, (n * 16 + c) * 2) = f2s(p);
      }
    }
    // PV: A = P from LDS, B = V^T rows from global
#pragma unroll
    for (int ks = 0; ks < 2; ks++) {
      short8 pa = *(short8*)swz_addr(PlW, c, ks * 64 + g * 16);
#pragma unroll
      for (int n = 0; n < 4; n++) {
        short8 vt = *(const short8*)&Vp[(size_t)(n * 16 + c) * SKVL + kt + ks * 32 + g * 8];
        ctxa[n] = __builtin_amdgcn_mfma_f32_16x16x32_bf16(pa, vt, ctxa[n], 0, 0, 0);
      }
    }
  }

  // epilogue: finish l reduction, normalize, store
  float inv[4];
#pragma unroll
  for (int r = 0; r < 4; r++) {
    float l = lpart[r];
#pragma unroll
    for (int off = 1; off < 16; off <<= 1) l += __shfl_xor(l, off);
    inv[r] = 1.0f / l;
  }
#pragma unroll
  for (int r = 0; r < 4; r++)
#pragma unroll
    for (int n = 0; n < 4; n++)
      O[(size_t)(b * SQL + q0 + g * 4 + r) * DIML + h * 64 + n * 16 + c] =
          f2s(ctxa[n][r] * inv[r]);
}

extern "C" void kernel_launch(void* const* d_in, const int* in_sizes, int n_in,
                              void* d_out, int out_size, void* d_ws, size_t ws_size,
                              hipStream_t stream)
{
  const float* x   = (const float*)d_in[0];
  const float* kc  = (const float*)d_in[1];
  const float* vc  = (const float*)d_in[2];
  const float* msk = (const float*)d_in[3];
  const float* Wq  = (const float*)d_in[4];
  const float* bq  = (const float*)d_in[5];
  const float* Wk  = (const float*)d_in[6];
  const float* bk  = (const float*)d_in[7];
  const float* Wv  = (const float*)d_in[8];
  const float* bv  = (const float*)d_in[9];
  const float* Wo  = (const float*)d_in[10];
  const float* bo  = (const float*)d_in[11];

  float* outf = (float*)d_out;
  float* kout = outf + 4194304;    // [B][4096][1024] f32
  float* vout = outf + 12582912;

  short* ws_s = (short*)d_ws;
  short* WT   = ws_s;                           // 4 x 1Mi bf16 = 8 MB
  short* xbf  = ws_s + (size_t)4 * 1048576;     // [4096][1024] bf16 (later: ctx)
  short* qbf  = ws_s + (size_t)8 * 1048576;     // [4096][1024] bf16 (pre-scaled)
  short* Kbf  = ws_s + (size_t)12 * 1048576;    // [B][4096][1024] bf16
  short* VTb  = ws_s + (size_t)20 * 1048576;    // [B*16][64][4096] bf16
  short* ctxb = xbf;

  convert_x_kernel<<<2048, 256, 0, stream>>>(x, xbf);
  transpose_w_kernel<<<1024, 256, 0, stream>>>(Wq, Wk, Wv, Wo, WT);
  copy_cache_kernel<<<4096, 256, 0, stream>>>(kc, vc, outf, Kbf);
  gemm_bt_bias<<<256, 256, 0, stream>>>(xbf, WT,               bq, nullptr, qbf, 2048, 0, 0.125f);
  gemm_bt_bias<<<256, 256, 0, stream>>>(xbf, WT + 1048576,     bk, kout, Kbf,   4096, 2048, 1.0f);
  gemm_bt_bias<<<256, 256, 0, stream>>>(xbf, WT + 2 * 1048576, bv, vout, nullptr, 4096, 2048, 1.0f);
  transpose_v_kernel<<<2048, 256, 0, stream>>>(vout, VTb);
  attn_kernel<<<1024, 256, 0, stream>>>(qbf, Kbf, VTb, msk, ctxb);
  gemm_bt_bias<<<256, 256, 0, stream>>>(ctxb, WT + 3 * 1048576, bo, outf, nullptr, 2048, 0, 1.0f);
}